// Round 4
// baseline (204.323 us; speedup 1.0000x reference)
//
#include <hip/hip_runtime.h>

// KANN_4578435137547: quadratic Lagrange FEM basis + weight contraction.
// Single-pass writer, one block per (sample, array). Dense stores are
// NONTEMPORAL (streaming) to match fillBuffer's ~6.7 TB/s store path.
// Outputs (flat f32): t[32768], dt[32768], ddt[32768],
//   phi/dphi/ddphi each [32768][2049].

#define KN_NODES    2049
#define KN_SAMPLES  4096
#define KN_IK       (KN_SAMPLES * 8)                   // 32768
#define KN_HEAD     (3 * KN_IK)                        // 98304
#define KN_PHI_LEN  ((size_t)KN_IK * KN_NODES)         // 67,141,632
#define KN_ROWF     (8 * KN_NODES)                     // 16392 floats per block
#define KN_NF4      (KN_ROWF / 4)                      // 4098 float4 per block

typedef float kn_f4 __attribute__((ext_vector_type(4)));

__global__ __launch_bounds__(256)
void KANN_all(const float* __restrict__ x, const float* __restrict__ w,
              float* __restrict__ out) {
    const int i = blockIdx.x;     // sample
    const int y = blockIdx.y;     // 0=phi, 1=dphi, 2=ddphi

    // Wave-uniform per block: coordinate + basis values.
    float xv  = x[i];
    float xs  = 2048.0f * xv;
    float fid = floorf(0.5f * xs);
    fid = fminf(fmaxf(fid, 0.0f), 1023.0f);
    int   nl  = 2 * (int)fid;                 // even, [0, 2046]
    float x_t = xs - (float)nl - 1.0f;        // [-1, 1]

    float b0, b1, b2;
    if (y == 0)      { b0 = 0.5f * x_t * (x_t - 1.0f); b1 = 1.0f - x_t * x_t; b2 = 0.5f * x_t * (x_t + 1.0f); }
    else if (y == 1) { b0 = (x_t - 0.5f) * 2048.0f; b1 = -4096.0f * x_t; b2 = (x_t + 0.5f) * 2048.0f; }
    else             { b0 = 4194304.0f; b1 = -8388608.0f; b2 = 4194304.0f; }

    // Head contractions folded into y==0 blocks, lanes 0..7 (k index).
    if (y == 0 && threadIdx.x < 8) {
        int k = threadIdx.x;
        const float* wk = w + k * KN_NODES + nl;
        float w0 = wk[0], w1 = wk[1], w2 = wk[2];
        float p0 = 0.5f * x_t * (x_t - 1.0f);
        float p1 = 1.0f - x_t * x_t;
        float p2 = 0.5f * x_t * (x_t + 1.0f);
        int ik = i * 8 + k;
        out[ik]             = w0 * p0 + w1 * p1 + w2 * p2;
        out[KN_IK + ik]     = (w0 * (x_t - 0.5f) - 2.0f * w1 * x_t + w2 * (x_t + 0.5f)) * 2048.0f;
        out[2 * KN_IK + ik] = (w0 - 2.0f * w1 + w2) * 4194304.0f;
    }

    // Dense region: rows 8i..8i+7 of array y, 4098 float4s, 16B-aligned base.
    float* base = out + KN_HEAD + (size_t)y * KN_PHI_LEN + (size_t)i * KN_ROWF;
    const kn_f4 zero4 = {0.0f, 0.0f, 0.0f, 0.0f};

    for (int f = threadIdx.x; f < KN_NF4; f += 256) {
        int e0 = f << 2;
        int r  = e0 >> 11;                    // 2049 = 2^11 + 1
        int c  = (e0 & 2047) - r;
        if (c < 0) { r -= 1; c += KN_NODES; } // c = col of first element, [0,2048]
        int  d0   = c - nl;
        bool hot  = (d0 >= -3 && d0 <= 2) || (c >= 2046 && nl <= 2);
        if (__builtin_expect(__any(hot), 0)) {
            kn_f4 v;
#pragma unroll
            for (int j = 0; j < 4; ++j) {
                int cj = c + j;
                if (cj > 2048) cj -= KN_NODES;   // wraps into next row (same nl)
                int d = cj - nl;
                v[j] = (d == 0) ? b0 : ((d == 1) ? b1 : ((d == 2) ? b2 : 0.0f));
            }
            __builtin_nontemporal_store(v, reinterpret_cast<kn_f4*>(base + e0));
        } else {
            __builtin_nontemporal_store(zero4, reinterpret_cast<kn_f4*>(base + e0));
        }
    }
}

extern "C" void kernel_launch(void* const* d_in, const int* in_sizes, int n_in,
                              void* d_out, int out_size, void* d_ws, size_t ws_size,
                              hipStream_t stream) {
    const float* x = (const float*)d_in[0];
    const float* w = (const float*)d_in[1];
    float* out = (float*)d_out;
    KANN_all<<<dim3(KN_SAMPLES, 3), dim3(256), 0, stream>>>(x, w, out);
}

// Round 5
// 151.713 us; speedup vs baseline: 1.3468x; 1.3468x over previous
//
#include <hip/hip_runtime.h>

// KANN_4578435137547: quadratic Lagrange FEM basis + weight contraction.
// Structure: hipMemsetAsync zeroes the whole output at the fill-kernel's
// ~6.7 TB/s, then ONE wide latency-optimized scatter pass writes the
// ~1.2 MB of nonzeros: 32768 head triples + 98304 three-float windows.
// Outputs (flat f32): t[32768], dt[32768], ddt[32768],
//   phi/dphi/ddphi each [32768][2049].

#define KN_NODES    2049
#define KN_SAMPLES  4096
#define KN_IK       (KN_SAMPLES * 8)                   // 32768
#define KN_HEAD     (3 * KN_IK)                        // 98304
#define KN_PHI_LEN  ((size_t)KN_IK * KN_NODES)         // 67,141,632

__device__ __forceinline__ void kann_coord(float xv, int& nl, float& x_t) {
    float xs  = 2048.0f * xv;
    float fid = floorf(0.5f * xs);
    fid = fminf(fmaxf(fid, 0.0f), 1023.0f);
    nl  = 2 * (int)fid;                  // even, [0, 2046]
    x_t = xs - (float)nl - 1.0f;         // local coord in [-1, 1]
}

// 131072 threads: t < 32768 -> head contraction (i,k); else window scatter (y,i,k).
__global__ __launch_bounds__(256)
void KANN_scatter(const float* __restrict__ x, const float* __restrict__ w,
                  float* __restrict__ out) {
    int t = blockIdx.x * 256 + threadIdx.x;

    if (t < KN_IK) {
        // Head: t/dt/ddt contractions, coalesced stores.
        int ik = t;
        int i = ik >> 3, k = ik & 7;
        int nl; float x_t; kann_coord(x[i], nl, x_t);
        const float* wk = w + k * KN_NODES + nl;
        float w0 = wk[0], w1 = wk[1], w2 = wk[2];
        float p0 = 0.5f * x_t * (x_t - 1.0f);
        float p1 = 1.0f - x_t * x_t;
        float p2 = 0.5f * x_t * (x_t + 1.0f);
        out[ik]             = w0 * p0 + w1 * p1 + w2 * p2;
        out[KN_IK + ik]     = (w0 * (x_t - 0.5f) - 2.0f * w1 * x_t + w2 * (x_t + 0.5f)) * 2048.0f;
        out[2 * KN_IK + ik] = (w0 - 2.0f * w1 + w2) * 4194304.0f;
    } else {
        // Window scatter: 3 floats into phi/dphi/ddphi row ik at col nl.
        int s = t - KN_IK;
        if (s >= 3 * KN_IK) return;
        int y  = s >> 15;                 // 0=phi, 1=dphi, 2=ddphi
        int ik = s & (KN_IK - 1);
        int i  = ik >> 3;
        int nl; float x_t; kann_coord(x[i], nl, x_t);
        float b0, b1, b2;
        if (y == 0)      { b0 = 0.5f * x_t * (x_t - 1.0f); b1 = 1.0f - x_t * x_t; b2 = 0.5f * x_t * (x_t + 1.0f); }
        else if (y == 1) { b0 = (x_t - 0.5f) * 2048.0f; b1 = -4096.0f * x_t; b2 = (x_t + 0.5f) * 2048.0f; }
        else             { b0 = 4194304.0f; b1 = -8388608.0f; b2 = 4194304.0f; }
        float* p = out + KN_HEAD + (size_t)y * KN_PHI_LEN + (size_t)ik * KN_NODES + nl;
        p[0] = b0; p[1] = b1; p[2] = b2;
    }
}

extern "C" void kernel_launch(void* const* d_in, const int* in_sizes, int n_in,
                              void* d_out, int out_size, void* d_ws, size_t ws_size,
                              hipStream_t stream) {
    const float* x = (const float*)d_in[0];
    const float* w = (const float*)d_in[1];
    float* out = (float*)d_out;

    hipMemsetAsync(out, 0, (size_t)out_size * sizeof(float), stream);

    const int total = 4 * KN_IK;                       // 131072 threads
    KANN_scatter<<<dim3(total / 256), dim3(256), 0, stream>>>(x, w, out);
}